// Round 1
// baseline (159.981 us; speedup 1.0000x reference)
//
#include <hip/hip_runtime.h>
#include <hip/hip_bf16.h>
#include <math.h>

// Problem constants (reference: B=4, N=8192, PIXEL_DIM=3).
#define BB   4
#define NN   8192
#define NSEG 8              // split-K segments over keys
#define SEGK (NN / NSEG)    // 1024 keys per segment
#define QPB  256            // queries per block == threads per block

// Workspace layout (16B aligned):
//   qs   : float4[B*N]          (pre-scaled q, w-component pad)      512 KB
//   kv   : float [B*N*6]        (k0,k1,k2,v0,v1,v2 per key)          768 KB
//   part : float4[B*N*NSEG]     (l, o0, o1, o2 partials)             4 MB
#define WS_QS_OFF   0
#define WS_KV_OFF   (512 * 1024)
#define WS_PART_OFF (1280 * 1024)

// ---------------------------------------------------------------------------
// Kernel 1: QKV projection.
// qkv[c] = x . W[c,:] + b[c];  q_j = row 3j, k_j = row 3j+1, v_j = row 3j+2
// (interleaved slicing per the reference's view(B,N,3,-1)[...,i]).
// q is pre-scaled by log2(e)/sqrt(3) so the attention kernel works directly
// in log2 domain with native v_exp_f32.
// ---------------------------------------------------------------------------
__global__ __launch_bounds__(256) void qkv_kernel(const float* __restrict__ x,
                                                  const float* __restrict__ W,
                                                  const float* __restrict__ bias,
                                                  float4* __restrict__ qs,
                                                  float* __restrict__ kv) {
    int p = blockIdx.x * 256 + threadIdx.x;   // 0 .. B*N-1
    float x0 = x[p * 3 + 0];
    float x1 = x[p * 3 + 1];
    float x2 = x[p * 3 + 2];
    const float C = 1.4426950408889634f / 1.7320508075688772f;  // log2(e)/sqrt(3)

    float o[9];
#pragma unroll
    for (int c = 0; c < 9; ++c) {
        o[c] = fmaf(x0, W[c * 3 + 0],
               fmaf(x1, W[c * 3 + 1],
               fmaf(x2, W[c * 3 + 2], bias[c])));
    }
    qs[p] = make_float4(o[0] * C, o[3] * C, o[6] * C, 0.0f);
    float* kvp = kv + (size_t)p * 6;
    kvp[0] = o[1]; kvp[1] = o[4]; kvp[2] = o[7];   // k
    kvp[3] = o[2]; kvp[4] = o[5]; kvp[5] = o[8];   // v
}

// ---------------------------------------------------------------------------
// Kernel 2: split-K attention partials.
// grid = (NSEG, N/QPB, B). Each block stages its key segment (1024 keys x
// 6 floats = 24 KB) into LDS, then each thread owns one query and walks the
// segment. All 64 lanes read the SAME key -> LDS broadcast, conflict-free,
// co-issued with VALU. Fixed m=0 softmax: scores in log2 units are bounded
// |s| <~ 20 here (overflow would need |s| > 120), so no online max needed;
// exact normalization happens in the combine kernel.
// ---------------------------------------------------------------------------
__global__ __launch_bounds__(256) void attn_part_kernel(const float4* __restrict__ qs,
                                                        const float* __restrict__ kv,
                                                        float4* __restrict__ part) {
    __shared__ float4 lds4[SEGK * 6 / 4];   // 1536 float4 = 24 KB
    float* lds = (float*)lds4;

    const int seg = blockIdx.x;
    const int qt  = blockIdx.y;
    const int b   = blockIdx.z;
    const int t   = threadIdx.x;

    // Stage kv segment: 1536 float4, 256 threads -> 6 coalesced float4 each.
    const float4* src = (const float4*)(kv + (size_t)(b * NN + seg * SEGK) * 6);
#pragma unroll
    for (int i = 0; i < (SEGK * 6 / 4) / 256; ++i)
        lds4[i * 256 + t] = src[i * 256 + t];
    __syncthreads();

    const int q = b * NN + qt * QPB + t;
    const float4 qv = qs[q];

    float l = 0.0f, o0 = 0.0f, o1 = 0.0f, o2 = 0.0f;
#pragma unroll 4
    for (int j = 0; j < SEGK; ++j) {
        float k0 = lds[j * 6 + 0];
        float k1 = lds[j * 6 + 1];
        float k2 = lds[j * 6 + 2];
        float v0 = lds[j * 6 + 3];
        float v1 = lds[j * 6 + 4];
        float v2 = lds[j * 6 + 5];
        float s = fmaf(qv.x, k0, fmaf(qv.y, k1, qv.z * k2));
        float p = __builtin_amdgcn_exp2f(s);   // v_exp_f32
        l += p;
        o0 = fmaf(p, v0, o0);
        o1 = fmaf(p, v1, o1);
        o2 = fmaf(p, v2, o2);
    }
    part[(size_t)q * NSEG + seg] = make_float4(l, o0, o1, o2);
}

// ---------------------------------------------------------------------------
// Kernel 3: combine partials + residual.
// ---------------------------------------------------------------------------
__global__ __launch_bounds__(256) void combine_kernel(const float4* __restrict__ part,
                                                      const float* __restrict__ x,
                                                      float* __restrict__ out) {
    int q = blockIdx.x * 256 + threadIdx.x;   // 0 .. B*N-1
    float L = 0.0f, O0 = 0.0f, O1 = 0.0f, O2 = 0.0f;
#pragma unroll
    for (int s = 0; s < NSEG; ++s) {
        float4 p = part[(size_t)q * NSEG + s];
        L  += p.x;
        O0 += p.y;
        O1 += p.z;
        O2 += p.w;
    }
    out[q * 3 + 0] = O0 / L + x[q * 3 + 0];
    out[q * 3 + 1] = O1 / L + x[q * 3 + 1];
    out[q * 3 + 2] = O2 / L + x[q * 3 + 2];
}

extern "C" void kernel_launch(void* const* d_in, const int* in_sizes, int n_in,
                              void* d_out, int out_size, void* d_ws, size_t ws_size,
                              hipStream_t stream) {
    const float* x    = (const float*)d_in[0];  // (B, N, 3)
    const float* W    = (const float*)d_in[1];  // (9, 3)
    const float* bias = (const float*)d_in[2];  // (9,)
    float* out = (float*)d_out;                 // (B, N, 3)

    char* ws = (char*)d_ws;
    float4* qs   = (float4*)(ws + WS_QS_OFF);
    float*  kv   = (float*) (ws + WS_KV_OFF);
    float4* part = (float4*)(ws + WS_PART_OFF);

    qkv_kernel<<<BB * NN / 256, 256, 0, stream>>>(x, W, bias, qs, kv);

    dim3 g2(NSEG, NN / QPB, BB);
    attn_part_kernel<<<g2, 256, 0, stream>>>(qs, kv, part);

    combine_kernel<<<BB * NN / 256, 256, 0, stream>>>(part, x, out);
}

// Round 2
// 133.108 us; speedup vs baseline: 1.2019x; 1.2019x over previous
//
#include <hip/hip_runtime.h>
#include <hip/hip_bf16.h>
#include <math.h>

// Problem constants (reference: B=4, N=8192, PIXEL_DIM=3).
#define BB   4
#define NN   8192
#define BN   (BB * NN)
#define QQ   4              // queries per thread (kv-load amortization)

// Workspace layout (16B aligned):
//   qs   : float4[BN]            (pre-scaled q, w pad)               512 KB
//   kv8  : float4[BN*2]          (k0,k1,k2,v0 | v1,v2,pad,pad)       1 MB
//   part : float4[NSEG*BN]       (l, o0, o1, o2 partials)            up to 16.8 MB
#define WS_QS_OFF   0
#define WS_KV_OFF   (512 * 1024)
#define WS_PART_OFF (1536 * 1024)

// ---------------------------------------------------------------------------
// Kernel 1: QKV projection. q_j = qkv row 3j, k_j = 3j+1, v_j = 3j+2
// (interleaved per reference view(B,N,3,-1)[...,i]). q pre-scaled by
// log2(e)/sqrt(3) so attention works in log2 domain with native v_exp_f32.
// kv padded to 32 B/key so the attention kernel reads 2x ds_read_b128.
// ---------------------------------------------------------------------------
__global__ __launch_bounds__(256) void qkv_kernel(const float* __restrict__ x,
                                                  const float* __restrict__ W,
                                                  const float* __restrict__ bias,
                                                  float4* __restrict__ qs,
                                                  float4* __restrict__ kv8) {
    int p = blockIdx.x * 256 + threadIdx.x;   // 0 .. BN-1
    float x0 = x[p * 3 + 0];
    float x1 = x[p * 3 + 1];
    float x2 = x[p * 3 + 2];
    const float C = 1.4426950408889634f / 1.7320508075688772f;  // log2(e)/sqrt(3)

    float o[9];
#pragma unroll
    for (int c = 0; c < 9; ++c) {
        o[c] = fmaf(x0, W[c * 3 + 0],
               fmaf(x1, W[c * 3 + 1],
               fmaf(x2, W[c * 3 + 2], bias[c])));
    }
    qs[p] = make_float4(o[0] * C, o[3] * C, o[6] * C, 0.0f);
    kv8[p * 2 + 0] = make_float4(o[1], o[4], o[7], o[2]);  // k0,k1,k2,v0
    kv8[p * 2 + 1] = make_float4(o[5], o[8], 0.0f, 0.0f);  // v1,v2,pad
}

// ---------------------------------------------------------------------------
// Kernel 2: split-K attention partials, Q=4 queries per thread.
// grid = (NSEG, NN/(256*QQ), BB). Block stages its key segment (32 B/key)
// into LDS; every lane reads the SAME key (broadcast, conflict-free) via two
// ds_read_b128, amortized over 4 queries -> VALU-bound (~22 cyc/key/query/wave).
// Fixed m=0 softmax: log2-domain scores bounded |s|<~20 (overflow needs >120),
// exact normalization in combine.
// ---------------------------------------------------------------------------
template <int NSEG_T>
__global__ __launch_bounds__(256) void attn_part_kernel(const float4* __restrict__ qs,
                                                        const float4* __restrict__ kv8,
                                                        float4* __restrict__ part) {
    constexpr int SEGK_T = NN / NSEG_T;
    __shared__ float4 lds4[SEGK_T * 2];

    const int seg = blockIdx.x;
    const int qt  = blockIdx.y;
    const int b   = blockIdx.z;
    const int t   = threadIdx.x;

    // Stage: SEGK_T*2 float4, 256 threads, coalesced.
    const float4* src = kv8 + (size_t)(b * NN + seg * SEGK_T) * 2;
#pragma unroll
    for (int i = 0; i < (SEGK_T * 2) / 256; ++i)
        lds4[i * 256 + t] = src[i * 256 + t];
    __syncthreads();

    const int qbase = b * NN + qt * (256 * QQ) + t;
    float4 qv[QQ];
#pragma unroll
    for (int u = 0; u < QQ; ++u) qv[u] = qs[qbase + 256 * u];

    float l[QQ], o0[QQ], o1[QQ], o2[QQ];
#pragma unroll
    for (int u = 0; u < QQ; ++u) { l[u] = 0.f; o0[u] = 0.f; o1[u] = 0.f; o2[u] = 0.f; }

#pragma unroll 2
    for (int j = 0; j < SEGK_T; ++j) {
        float4 a = lds4[2 * j];       // k0,k1,k2,v0
        float4 c = lds4[2 * j + 1];   // v1,v2,-,-
#pragma unroll
        for (int u = 0; u < QQ; ++u) {
            float s = fmaf(qv[u].x, a.x, fmaf(qv[u].y, a.y, qv[u].z * a.z));
            float p = __builtin_amdgcn_exp2f(s);   // v_exp_f32
            l[u] += p;
            o0[u] = fmaf(p, a.w, o0[u]);
            o1[u] = fmaf(p, c.x, o1[u]);
            o2[u] = fmaf(p, c.y, o2[u]);
        }
    }

    float4* dst = part + (size_t)seg * BN + qbase;
#pragma unroll
    for (int u = 0; u < QQ; ++u)
        dst[256 * u] = make_float4(l[u], o0[u], o1[u], o2[u]);
}

// ---------------------------------------------------------------------------
// Kernel 3: combine partials + residual. part[s] laid out plane-major so both
// the attn stores and these reads are lane-coalesced.
// ---------------------------------------------------------------------------
__global__ __launch_bounds__(256) void combine_kernel(const float4* __restrict__ part,
                                                      const float* __restrict__ x,
                                                      float* __restrict__ out,
                                                      int nseg) {
    int q = blockIdx.x * 256 + threadIdx.x;   // 0 .. BN-1
    float L = 0.0f, O0 = 0.0f, O1 = 0.0f, O2 = 0.0f;
    for (int s = 0; s < nseg; ++s) {
        float4 p = part[(size_t)s * BN + q];
        L  += p.x;
        O0 += p.y;
        O1 += p.z;
        O2 += p.w;
    }
    float inv = 1.0f / L;
    out[q * 3 + 0] = fmaf(O0, inv, x[q * 3 + 0]);
    out[q * 3 + 1] = fmaf(O1, inv, x[q * 3 + 1]);
    out[q * 3 + 2] = fmaf(O2, inv, x[q * 3 + 2]);
}

template <int NSEG_T>
static void launch_all(const float* x, const float* W, const float* bias,
                       float4* qs, float4* kv8, float4* part, float* out,
                       hipStream_t stream) {
    qkv_kernel<<<BN / 256, 256, 0, stream>>>(x, W, bias, qs, kv8);
    dim3 g2(NSEG_T, NN / (256 * QQ), BB);
    attn_part_kernel<NSEG_T><<<g2, 256, 0, stream>>>(qs, kv8, part);
    combine_kernel<<<BN / 256, 256, 0, stream>>>(part, x, out, NSEG_T);
}

extern "C" void kernel_launch(void* const* d_in, const int* in_sizes, int n_in,
                              void* d_out, int out_size, void* d_ws, size_t ws_size,
                              hipStream_t stream) {
    const float* x    = (const float*)d_in[0];  // (B, N, 3)
    const float* W    = (const float*)d_in[1];  // (9, 3)
    const float* bias = (const float*)d_in[2];  // (9,)
    float* out = (float*)d_out;                 // (B, N, 3)

    char* ws = (char*)d_ws;
    float4* qs   = (float4*)(ws + WS_QS_OFF);
    float4* kv8  = (float4*)(ws + WS_KV_OFF);
    float4* part = (float4*)(ws + WS_PART_OFF);

    // Deterministic tier select on constant ws_size (same work every call).
    size_t need32 = (size_t)WS_PART_OFF + (size_t)32 * BN * 16;  // ~18.3 MB
    size_t need16 = (size_t)WS_PART_OFF + (size_t)16 * BN * 16;  // ~9.9 MB
    if (ws_size >= need32)      launch_all<32>(x, W, bias, qs, kv8, part, out, stream);
    else if (ws_size >= need16) launch_all<16>(x, W, bias, qs, kv8, part, out, stream);
    else                        launch_all<8>(x, W, bias, qs, kv8, part, out, stream);
}